// Round 4
// baseline (515.761 us; speedup 1.0000x reference)
//
#include <hip/hip_runtime.h>
#include <hip/hip_bf16.h>
#include <stdint.h>

#define M_DIM 8192
#define K_DIM 512
#define N_DIM 32000
#define NTILES 4000   // (8192/256) * (32000/256) = 32 * 125
#define NBLK 256
#define TPB_Q 15      // 4000 / 256
#define TPB_R 160     // 4000 - 15*256

typedef short bf16x8 __attribute__((ext_vector_type(8)));
typedef float f32x4 __attribute__((ext_vector_type(4)));
typedef unsigned short u16;

__device__ __forceinline__ u16 f2bf(float f) {
  union { float f; uint32_t u; } v; v.f = f;
  uint32_t r = (v.u + 0x7fffu + ((v.u >> 16) & 1u)) >> 16;  // RNE
  return (u16)r;
}

// ---------------- Kernel 1: row-l2norm of x -> bf16, one wave per row ----------------
__global__ void k_xnorm(const float* __restrict__ x, u16* __restrict__ xn) {
  int row = (blockIdx.x * blockDim.x + threadIdx.x) >> 6;
  int lane = threadIdx.x & 63;
  const float4* rp = (const float4*)(x + (size_t)row * K_DIM);
  float4 a = rp[lane];
  float4 b = rp[lane + 64];
  float s = a.x*a.x + a.y*a.y + a.z*a.z + a.w*a.w
          + b.x*b.x + b.y*b.y + b.z*b.z + b.w*b.w;
#pragma unroll
  for (int off = 32; off > 0; off >>= 1) s += __shfl_xor(s, off, 64);
  float r = rsqrtf(fmaxf(s, 1e-12f));
  ushort4 o0 = make_ushort4(f2bf(a.x*r), f2bf(a.y*r), f2bf(a.z*r), f2bf(a.w*r));
  ushort4 o1 = make_ushort4(f2bf(b.x*r), f2bf(b.y*r), f2bf(b.z*r), f2bf(b.w*r));
  ushort4* dst = (ushort4*)(xn + (size_t)row * K_DIM);
  dst[lane] = o0;
  dst[lane + 64] = o1;
}

// ---------------- Kernel 2: column sumsq of w -> rsqrt factors ----------------
__global__ void k_wnorm(const float* __restrict__ w, float* __restrict__ cn) {
  int c = blockIdx.x * 256 + threadIdx.x;
  int rg = threadIdx.y;  // 0..3
  const float* p = w + (size_t)rg * 128 * N_DIM + c;
  float s = 0.f;
#pragma unroll 8
  for (int r = 0; r < 128; ++r) {
    float v = p[(size_t)r * N_DIM];
    s = fmaf(v, v, s);
  }
  __shared__ float red[4][256];
  red[rg][threadIdx.x] = s;
  __syncthreads();
  if (rg == 0) {
    float t = red[0][threadIdx.x] + red[1][threadIdx.x]
            + red[2][threadIdx.x] + red[3][threadIdx.x];
    cn[c] = rsqrtf(fmaxf(t, 1e-12f));
  }
}

// ---------------- Kernel 3: transpose + scale + cast: w[512][32000] -> wT[32000][512] bf16 ----------------
__global__ void k_wtrans(const float* __restrict__ w, const float* __restrict__ cn,
                         u16* __restrict__ wT) {
  __shared__ u16 tile[64][68];
  int c0 = blockIdx.x * 64;
  int r0 = blockIdx.y * 64;
  int tc = threadIdx.x & 63;
  int tw = threadIdx.x >> 6;  // 0..3
  float scale = cn[c0 + tc];
#pragma unroll
  for (int i = 0; i < 16; ++i) {
    int r = i * 4 + tw;
    float v = w[(size_t)(r0 + r) * N_DIM + c0 + tc];
    tile[tc][r] = f2bf(v * scale);
  }
  __syncthreads();
  int cc = threadIdx.x >> 4;        // 0..15
  int rr = (threadIdx.x & 15) * 4;  // 0..60
#pragma unroll
  for (int i = 0; i < 4; ++i) {
    int c = cc + i * 16;
    ushort4 v = *(const ushort4*)&tile[c][rr];
    *(ushort4*)(wT + (size_t)(c0 + c) * K_DIM + r0 + rr) = v;
  }
}

// ---------------- Kernel 4: PERSISTENT 256x256 GEMM, 8 waves, 4-phase K-tiles ----------------
// Each block owns a contiguous chunk of 15-16 output tiles; the double-buffered
// pipeline runs seamlessly across tile boundaries (stage (t+1,0) during (t,7)).
__global__ __launch_bounds__(512, 2) void k_gemm(const u16* __restrict__ A,
                                                 const u16* __restrict__ Bt,
                                                 float* __restrict__ C) {
  __shared__ u16 sm[2][32768];  // per buf: A [256][64] @0, B [256][64] @16384
  constexpr int BOFF = 16384;

  const int b = blockIdx.x;
  const int cnt = TPB_Q + (b < TPB_R ? 1 : 0);
  int t = b * TPB_Q + (b < TPB_R ? b : TPB_R);

  const int tid = threadIdx.x;
  const int lane = tid & 63;
  const int w = tid >> 6;   // 0..7
  const int wr = w >> 2;    // 0..1
  const int wc = w & 3;     // 0..3
  const int la = lane & 15;
  const int lk = lane >> 4;
  const int rx = la & 7;
  const int s0 = ((0 + lk) ^ rx) * 8;  // swizzled elem-col, kk=0
  const int s1 = ((4 + lk) ^ rx) * 8;  // swizzled elem-col, kk=32

  // staging geometry (rule #21: linear LDS dest + inverse-swizzled global src)
  const int srow = tid >> 3;
  const int sgl = ((tid & 7) ^ (srow & 7)) * 8;
  const int ldst = srow * 64 + (tid & 7) * 8;
  const int arow0 = (wr * 128 + la) * 64;
  const int brow0 = (wc * 64 + la) * 64;

  int bm = t / 125;
  int bn = t - bm * 125;
  const u16* ag = A  + (size_t)(bm * 256 + srow) * K_DIM + sgl;
  const u16* bg = Bt + (size_t)(bn * 256 + srow) * K_DIM + sgl;

  f32x4 acc[8][4] = {};

  // prologue: stage (t, kt=0) into buf 0
#pragma unroll
  for (int i = 0; i < 4; ++i)
    __builtin_amdgcn_global_load_lds(
        (const __attribute__((address_space(1))) void*)(ag + (size_t)i * 64 * K_DIM),
        (__attribute__((address_space(3))) void*)&sm[0][i * 4096 + ldst], 16, 0, 0);
#pragma unroll
  for (int i = 0; i < 4; ++i)
    __builtin_amdgcn_global_load_lds(
        (const __attribute__((address_space(1))) void*)(bg + (size_t)i * 64 * K_DIM),
        (__attribute__((address_space(3))) void*)&sm[0][BOFF + i * 4096 + ldst], 16, 0, 0);
  __syncthreads();

  for (int ti = 0; ti < cnt; ++ti) {
    // next tile's staging bases
    int bn1 = bn + 1, bm1 = bm;
    if (bn1 == 125) { bn1 = 0; bm1 = bm + 1; }
    const u16* agn = A  + (size_t)(bm1 * 256 + srow) * K_DIM + sgl;
    const u16* bgn = Bt + (size_t)(bn1 * 256 + srow) * K_DIM + sgl;
    const bool last_tile = (ti + 1 == cnt);

    for (int kt = 0; kt < 8; ++kt) {
      const int cur = kt & 1;
      const int nxt = cur ^ 1;
      const bool pf = (kt < 7) || !last_tile;
      const u16* agk = (kt < 7) ? (ag + (kt + 1) * 64) : agn;
      const u16* bgk = (kt < 7) ? (bg + (kt + 1) * 64) : bgn;

      bf16x8 bf[4][2];

      // ---- phase 1: m = 0,1 ; read all B frags; stage next A ----
      {
#pragma unroll
        for (int n = 0; n < 4; ++n) {
          bf[n][0] = *(const bf16x8*)&sm[cur][BOFF + brow0 + n * 1024 + s0];
          bf[n][1] = *(const bf16x8*)&sm[cur][BOFF + brow0 + n * 1024 + s1];
        }
        bf16x8 af[2][2];
#pragma unroll
        for (int m = 0; m < 2; ++m) {
          af[m][0] = *(const bf16x8*)&sm[cur][arow0 + m * 1024 + s0];
          af[m][1] = *(const bf16x8*)&sm[cur][arow0 + m * 1024 + s1];
        }
        if (pf) {
#pragma unroll
          for (int i = 0; i < 4; ++i)
            __builtin_amdgcn_global_load_lds(
                (const __attribute__((address_space(1))) void*)(agk + (size_t)i * 64 * K_DIM),
                (__attribute__((address_space(3))) void*)&sm[nxt][i * 4096 + ldst], 16, 0, 0);
        }
        __builtin_amdgcn_s_barrier();
        asm volatile("s_waitcnt lgkmcnt(0)" ::: "memory");
        __builtin_amdgcn_sched_barrier(0);
        __builtin_amdgcn_s_setprio(1);
#pragma unroll
        for (int m = 0; m < 2; ++m)
#pragma unroll
          for (int n = 0; n < 4; ++n) {
            acc[m][n] = __builtin_amdgcn_mfma_f32_16x16x32_bf16(af[m][0], bf[n][0], acc[m][n], 0, 0, 0);
            acc[m][n] = __builtin_amdgcn_mfma_f32_16x16x32_bf16(af[m][1], bf[n][1], acc[m][n], 0, 0, 0);
          }
        __builtin_amdgcn_s_setprio(0);
        __builtin_amdgcn_s_barrier();
      }

      // ---- phases 2..4: m = 2p..2p+1 ; phase 2 stages next B ----
#pragma unroll
      for (int p = 1; p < 4; ++p) {
        bf16x8 af[2][2];
#pragma unroll
        for (int m = 0; m < 2; ++m) {
          af[m][0] = *(const bf16x8*)&sm[cur][arow0 + (p * 2 + m) * 1024 + s0];
          af[m][1] = *(const bf16x8*)&sm[cur][arow0 + (p * 2 + m) * 1024 + s1];
        }
        if (p == 1 && pf) {
#pragma unroll
          for (int i = 0; i < 4; ++i)
            __builtin_amdgcn_global_load_lds(
                (const __attribute__((address_space(1))) void*)(bgk + (size_t)i * 64 * K_DIM),
                (__attribute__((address_space(3))) void*)&sm[nxt][BOFF + i * 4096 + ldst], 16, 0, 0);
        }
        __builtin_amdgcn_s_barrier();
        asm volatile("s_waitcnt lgkmcnt(0)" ::: "memory");
        __builtin_amdgcn_sched_barrier(0);
        __builtin_amdgcn_s_setprio(1);
#pragma unroll
        for (int m = 0; m < 2; ++m)
#pragma unroll
          for (int n = 0; n < 4; ++n) {
            acc[p * 2 + m][n] = __builtin_amdgcn_mfma_f32_16x16x32_bf16(af[m][0], bf[n][0], acc[p * 2 + m][n], 0, 0, 0);
            acc[p * 2 + m][n] = __builtin_amdgcn_mfma_f32_16x16x32_bf16(af[m][1], bf[n][1], acc[p * 2 + m][n], 0, 0, 0);
          }
        __builtin_amdgcn_s_setprio(0);
        if (p < 3) __builtin_amdgcn_s_barrier();
      }

      __syncthreads();  // drains staging for next buffer; also clears old stores (readout-fast)
    }

    // ---- epilogue for tile (bm, bn): nontemporal fp32 stores, then reset acc ----
    {
      const size_t crow0 = (size_t)bm * 256 + wr * 128 + lk * 4;
      const int ccol0 = bn * 256 + wc * 64 + la;
#pragma unroll
      for (int m = 0; m < 8; ++m)
#pragma unroll
        for (int j = 0; j < 4; ++j) {
          float* cp = C + (crow0 + m * 16 + j) * N_DIM + ccol0;
#pragma unroll
          for (int n = 0; n < 4; ++n)
            __builtin_nontemporal_store(acc[m][n][j], cp + n * 16);
        }
#pragma unroll
      for (int m = 0; m < 8; ++m)
#pragma unroll
        for (int n = 0; n < 4; ++n)
          acc[m][n] = (f32x4){0.f, 0.f, 0.f, 0.f};
    }

    bm = bm1; bn = bn1; ag = agn; bg = bgn;
  }
}

// ---------------- launch ----------------
extern "C" void kernel_launch(void* const* d_in, const int* in_sizes, int n_in,
                              void* d_out, int out_size, void* d_ws, size_t ws_size,
                              hipStream_t stream) {
  const float* x = (const float*)d_in[0];   // [8192, 512]
  const float* w = (const float*)d_in[1];   // [512, 32000]
  float* out = (float*)d_out;               // [8192, 32000]

  char* ws = (char*)d_ws;
  float* cn = (float*)ws;                                    // 32000 f32
  u16* xn = (u16*)(ws + 131072);                             // 8192*512 bf16
  u16* wT = (u16*)(ws + 131072 + (size_t)M_DIM * K_DIM * 2); // 32000*512 bf16

  k_xnorm<<<M_DIM / 4, 256, 0, stream>>>(x, xn);
  k_wnorm<<<N_DIM / 256, dim3(256, 4), 0, stream>>>(w, cn);
  k_wtrans<<<dim3(N_DIM / 64, K_DIM / 64), 256, 0, stream>>>(w, cn, wT);
  k_gemm<<<NBLK, 512, 0, stream>>>(xn, wT, out);
}

// Round 5
// 514.331 us; speedup vs baseline: 1.0028x; 1.0028x over previous
//
#include <hip/hip_runtime.h>
#include <hip/hip_bf16.h>
#include <stdint.h>

#define M_DIM 8192
#define K_DIM 512
#define N_DIM 32000
#define NTILES 4000   // (8192/256) * (32000/256) = 32 * 125
#define NBLK 256
#define TPB_Q 15      // 4000 / 256
#define TPB_R 160     // 4000 - 15*256

typedef short bf16x8 __attribute__((ext_vector_type(8)));
typedef float f32x4 __attribute__((ext_vector_type(4)));
typedef unsigned short u16;

__device__ __forceinline__ u16 f2bf(float f) {
  union { float f; uint32_t u; } v; v.f = f;
  uint32_t r = (v.u + 0x7fffu + ((v.u >> 16) & 1u)) >> 16;  // RNE
  return (u16)r;
}

// ---------------- Kernel 1: row-l2norm of x -> bf16, one wave per row ----------------
__global__ void k_xnorm(const float* __restrict__ x, u16* __restrict__ xn) {
  int row = (blockIdx.x * blockDim.x + threadIdx.x) >> 6;
  int lane = threadIdx.x & 63;
  const float4* rp = (const float4*)(x + (size_t)row * K_DIM);
  float4 a = rp[lane];
  float4 b = rp[lane + 64];
  float s = a.x*a.x + a.y*a.y + a.z*a.z + a.w*a.w
          + b.x*b.x + b.y*b.y + b.z*b.z + b.w*b.w;
#pragma unroll
  for (int off = 32; off > 0; off >>= 1) s += __shfl_xor(s, off, 64);
  float r = rsqrtf(fmaxf(s, 1e-12f));
  ushort4 o0 = make_ushort4(f2bf(a.x*r), f2bf(a.y*r), f2bf(a.z*r), f2bf(a.w*r));
  ushort4 o1 = make_ushort4(f2bf(b.x*r), f2bf(b.y*r), f2bf(b.z*r), f2bf(b.w*r));
  ushort4* dst = (ushort4*)(xn + (size_t)row * K_DIM);
  dst[lane] = o0;
  dst[lane + 64] = o1;
}

// ---------------- Kernel 2: column sumsq of w -> rsqrt factors ----------------
__global__ void k_wnorm(const float* __restrict__ w, float* __restrict__ cn) {
  int c = blockIdx.x * 256 + threadIdx.x;
  int rg = threadIdx.y;  // 0..3
  const float* p = w + (size_t)rg * 128 * N_DIM + c;
  float s = 0.f;
#pragma unroll 8
  for (int r = 0; r < 128; ++r) {
    float v = p[(size_t)r * N_DIM];
    s = fmaf(v, v, s);
  }
  __shared__ float red[4][256];
  red[rg][threadIdx.x] = s;
  __syncthreads();
  if (rg == 0) {
    float t = red[0][threadIdx.x] + red[1][threadIdx.x]
            + red[2][threadIdx.x] + red[3][threadIdx.x];
    cn[c] = rsqrtf(fmaxf(t, 1e-12f));
  }
}

// ---------------- Kernel 3: transpose + scale + cast: w[512][32000] -> wT[32000][512] bf16 ----------------
__global__ void k_wtrans(const float* __restrict__ w, const float* __restrict__ cn,
                         u16* __restrict__ wT) {
  __shared__ u16 tile[64][68];
  int c0 = blockIdx.x * 64;
  int r0 = blockIdx.y * 64;
  int tc = threadIdx.x & 63;
  int tw = threadIdx.x >> 6;  // 0..3
  float scale = cn[c0 + tc];
#pragma unroll
  for (int i = 0; i < 16; ++i) {
    int r = i * 4 + tw;
    float v = w[(size_t)(r0 + r) * N_DIM + c0 + tc];
    tile[tc][r] = f2bf(v * scale);
  }
  __syncthreads();
  int cc = threadIdx.x >> 4;        // 0..15
  int rr = (threadIdx.x & 15) * 4;  // 0..60
#pragma unroll
  for (int i = 0; i < 4; ++i) {
    int c = cc + i * 16;
    ushort4 v = *(const ushort4*)&tile[c][rr];
    *(ushort4*)(wT + (size_t)(c0 + c) * K_DIM + r0 + rr) = v;
  }
}

// ---------------- Kernel 4: PERSISTENT 256x256 GEMM, 8 waves, 4-phase K-tiles ----------------
// Each block owns a contiguous chunk of 15-16 output tiles; the double-buffered
// pipeline runs seamlessly across tile boundaries (stage (t+1,0) during (t,7)).
__global__ __launch_bounds__(512, 2) void k_gemm(const u16* __restrict__ A,
                                                 const u16* __restrict__ Bt,
                                                 float* __restrict__ C) {
  __shared__ u16 sm[2][32768];  // per buf: A [256][64] @0, B [256][64] @16384
  constexpr int BOFF = 16384;

  const int b = blockIdx.x;
  const int cnt = TPB_Q + (b < TPB_R ? 1 : 0);
  int t = b * TPB_Q + (b < TPB_R ? b : TPB_R);

  const int tid = threadIdx.x;
  const int lane = tid & 63;
  const int w = tid >> 6;   // 0..7
  const int wr = w >> 2;    // 0..1
  const int wc = w & 3;     // 0..3
  const int la = lane & 15;
  const int lk = lane >> 4;
  const int rx = la & 7;
  const int s0 = ((0 + lk) ^ rx) * 8;  // swizzled elem-col, kk=0
  const int s1 = ((4 + lk) ^ rx) * 8;  // swizzled elem-col, kk=32

  // staging geometry (rule #21: linear LDS dest + inverse-swizzled global src)
  const int srow = tid >> 3;
  const int sgl = ((tid & 7) ^ (srow & 7)) * 8;
  const int ldst = srow * 64 + (tid & 7) * 8;
  const int arow0 = (wr * 128 + la) * 64;
  const int brow0 = (wc * 64 + la) * 64;

  int bm = t / 125;
  int bn = t - bm * 125;
  const u16* ag = A  + (size_t)(bm * 256 + srow) * K_DIM + sgl;
  const u16* bg = Bt + (size_t)(bn * 256 + srow) * K_DIM + sgl;

  f32x4 acc[8][4] = {};

  // prologue: stage (t, kt=0) into buf 0
#pragma unroll
  for (int i = 0; i < 4; ++i)
    __builtin_amdgcn_global_load_lds(
        (const __attribute__((address_space(1))) void*)(ag + (size_t)i * 64 * K_DIM),
        (__attribute__((address_space(3))) void*)&sm[0][i * 4096 + ldst], 16, 0, 0);
#pragma unroll
  for (int i = 0; i < 4; ++i)
    __builtin_amdgcn_global_load_lds(
        (const __attribute__((address_space(1))) void*)(bg + (size_t)i * 64 * K_DIM),
        (__attribute__((address_space(3))) void*)&sm[0][BOFF + i * 4096 + ldst], 16, 0, 0);
  __syncthreads();

  for (int ti = 0; ti < cnt; ++ti) {
    // next tile's staging bases
    int bn1 = bn + 1, bm1 = bm;
    if (bn1 == 125) { bn1 = 0; bm1 = bm + 1; }
    const u16* agn = A  + (size_t)(bm1 * 256 + srow) * K_DIM + sgl;
    const u16* bgn = Bt + (size_t)(bn1 * 256 + srow) * K_DIM + sgl;
    const bool last_tile = (ti + 1 == cnt);

    for (int kt = 0; kt < 8; ++kt) {
      const int cur = kt & 1;
      const int nxt = cur ^ 1;
      const bool pf = (kt < 7) || !last_tile;
      const u16* agk = (kt < 7) ? (ag + (kt + 1) * 64) : agn;
      const u16* bgk = (kt < 7) ? (bg + (kt + 1) * 64) : bgn;

      bf16x8 bf[4][2];

      // ---- phase 1: m = 0,1 ; read all B frags; stage next A ----
      {
#pragma unroll
        for (int n = 0; n < 4; ++n) {
          bf[n][0] = *(const bf16x8*)&sm[cur][BOFF + brow0 + n * 1024 + s0];
          bf[n][1] = *(const bf16x8*)&sm[cur][BOFF + brow0 + n * 1024 + s1];
        }
        bf16x8 af[2][2];
#pragma unroll
        for (int m = 0; m < 2; ++m) {
          af[m][0] = *(const bf16x8*)&sm[cur][arow0 + m * 1024 + s0];
          af[m][1] = *(const bf16x8*)&sm[cur][arow0 + m * 1024 + s1];
        }
        if (pf) {
#pragma unroll
          for (int i = 0; i < 4; ++i)
            __builtin_amdgcn_global_load_lds(
                (const __attribute__((address_space(1))) void*)(agk + (size_t)i * 64 * K_DIM),
                (__attribute__((address_space(3))) void*)&sm[nxt][i * 4096 + ldst], 16, 0, 0);
        }
        __builtin_amdgcn_s_barrier();
        asm volatile("s_waitcnt lgkmcnt(0)" ::: "memory");
        __builtin_amdgcn_sched_barrier(0);
        __builtin_amdgcn_s_setprio(1);
#pragma unroll
        for (int m = 0; m < 2; ++m)
#pragma unroll
          for (int n = 0; n < 4; ++n) {
            acc[m][n] = __builtin_amdgcn_mfma_f32_16x16x32_bf16(af[m][0], bf[n][0], acc[m][n], 0, 0, 0);
            acc[m][n] = __builtin_amdgcn_mfma_f32_16x16x32_bf16(af[m][1], bf[n][1], acc[m][n], 0, 0, 0);
          }
        __builtin_amdgcn_s_setprio(0);
        __builtin_amdgcn_s_barrier();
      }

      // ---- phases 2..4: m = 2p..2p+1 ; phase 2 stages next B ----
#pragma unroll
      for (int p = 1; p < 4; ++p) {
        bf16x8 af[2][2];
#pragma unroll
        for (int m = 0; m < 2; ++m) {
          af[m][0] = *(const bf16x8*)&sm[cur][arow0 + (p * 2 + m) * 1024 + s0];
          af[m][1] = *(const bf16x8*)&sm[cur][arow0 + (p * 2 + m) * 1024 + s1];
        }
        if (p == 1 && pf) {
#pragma unroll
          for (int i = 0; i < 4; ++i)
            __builtin_amdgcn_global_load_lds(
                (const __attribute__((address_space(1))) void*)(bgk + (size_t)i * 64 * K_DIM),
                (__attribute__((address_space(3))) void*)&sm[nxt][BOFF + i * 4096 + ldst], 16, 0, 0);
        }
        __builtin_amdgcn_s_barrier();
        asm volatile("s_waitcnt lgkmcnt(0)" ::: "memory");
        __builtin_amdgcn_sched_barrier(0);
        __builtin_amdgcn_s_setprio(1);
#pragma unroll
        for (int m = 0; m < 2; ++m)
#pragma unroll
          for (int n = 0; n < 4; ++n) {
            acc[p * 2 + m][n] = __builtin_amdgcn_mfma_f32_16x16x32_bf16(af[m][0], bf[n][0], acc[p * 2 + m][n], 0, 0, 0);
            acc[p * 2 + m][n] = __builtin_amdgcn_mfma_f32_16x16x32_bf16(af[m][1], bf[n][1], acc[p * 2 + m][n], 0, 0, 0);
          }
        __builtin_amdgcn_s_setprio(0);
        if (p < 3) __builtin_amdgcn_s_barrier();
      }

      __syncthreads();  // drains staging for next buffer; also clears old stores (readout-fast)
    }

    // ---- epilogue for tile (bm, bn): nontemporal fp32 stores, then reset acc ----
    {
      const size_t crow0 = (size_t)bm * 256 + wr * 128 + lk * 4;
      const int ccol0 = bn * 256 + wc * 64 + la;
#pragma unroll
      for (int m = 0; m < 8; ++m)
#pragma unroll
        for (int j = 0; j < 4; ++j) {
          float* cp = C + (crow0 + m * 16 + j) * N_DIM + ccol0;
#pragma unroll
          for (int n = 0; n < 4; ++n)
            __builtin_nontemporal_store(acc[m][n][j], cp + n * 16);
        }
#pragma unroll
      for (int m = 0; m < 8; ++m)
#pragma unroll
        for (int n = 0; n < 4; ++n)
          acc[m][n] = (f32x4){0.f, 0.f, 0.f, 0.f};
    }

    bm = bm1; bn = bn1; ag = agn; bg = bgn;
  }
}

// ---------------- launch ----------------
extern "C" void kernel_launch(void* const* d_in, const int* in_sizes, int n_in,
                              void* d_out, int out_size, void* d_ws, size_t ws_size,
                              hipStream_t stream) {
  const float* x = (const float*)d_in[0];   // [8192, 512]
  const float* w = (const float*)d_in[1];   // [512, 32000]
  float* out = (float*)d_out;               // [8192, 32000]

  char* ws = (char*)d_ws;
  float* cn = (float*)ws;                                    // 32000 f32
  u16* xn = (u16*)(ws + 131072);                             // 8192*512 bf16
  u16* wT = (u16*)(ws + 131072 + (size_t)M_DIM * K_DIM * 2); // 32000*512 bf16

  k_xnorm<<<M_DIM / 4, 256, 0, stream>>>(x, xn);
  k_wnorm<<<N_DIM / 256, dim3(256, 4), 0, stream>>>(w, cn);
  k_wtrans<<<dim3(N_DIM / 64, K_DIM / 64), 256, 0, stream>>>(w, cn, wT);
  k_gemm<<<NBLK, 512, 0, stream>>>(xn, wT, out);
}

// Round 6
// 433.237 us; speedup vs baseline: 1.1905x; 1.1872x over previous
//
#include <hip/hip_runtime.h>
#include <hip/hip_bf16.h>
#include <stdint.h>

#define M_DIM 8192
#define K_DIM 512
#define N_DIM 32000

typedef short bf16x8 __attribute__((ext_vector_type(8)));
typedef float f32x4 __attribute__((ext_vector_type(4)));
typedef unsigned short u16;

__device__ __forceinline__ u16 f2bf(float f) {
  union { float f; uint32_t u; } v; v.f = f;
  uint32_t r = (v.u + 0x7fffu + ((v.u >> 16) & 1u)) >> 16;  // RNE
  return (u16)r;
}

// ---------------- Kernel 0: zero the column-sumsq accumulator ----------------
__global__ void k_zero(float* __restrict__ cn) {
  cn[blockIdx.x * 256 + threadIdx.x] = 0.f;
}

// ---------------- Kernel 1: row-l2norm of x -> bf16, one wave per row ----------------
__global__ void k_xnorm(const float* __restrict__ x, u16* __restrict__ xn) {
  int row = (blockIdx.x * blockDim.x + threadIdx.x) >> 6;
  int lane = threadIdx.x & 63;
  const float4* rp = (const float4*)(x + (size_t)row * K_DIM);
  float4 a = rp[lane];
  float4 b = rp[lane + 64];
  float s = a.x*a.x + a.y*a.y + a.z*a.z + a.w*a.w
          + b.x*b.x + b.y*b.y + b.z*b.z + b.w*b.w;
#pragma unroll
  for (int off = 32; off > 0; off >>= 1) s += __shfl_xor(s, off, 64);
  float r = rsqrtf(fmaxf(s, 1e-12f));
  ushort4 o0 = make_ushort4(f2bf(a.x*r), f2bf(a.y*r), f2bf(a.z*r), f2bf(a.w*r));
  ushort4 o1 = make_ushort4(f2bf(b.x*r), f2bf(b.y*r), f2bf(b.z*r), f2bf(b.w*r));
  ushort4* dst = (ushort4*)(xn + (size_t)row * K_DIM);
  dst[lane] = o0;
  dst[lane + 64] = o1;
}

// ---------------- Kernel 2: transpose + cast (UNNORMALIZED) + fused col-sumsq ----------------
// wT[32000][512] bf16 = w^T; cn[c] += sum_r w[r][c]^2 (atomics over 8 row-blocks)
__global__ void k_wtrans(const float* __restrict__ w, float* __restrict__ cn,
                         u16* __restrict__ wT) {
  __shared__ u16 tile[64][68];
  int c0 = blockIdx.x * 64;
  int r0 = blockIdx.y * 64;
  int tc = threadIdx.x & 63;
  int tw = threadIdx.x >> 6;  // 0..3
  float s = 0.f;
#pragma unroll
  for (int i = 0; i < 16; ++i) {
    int r = i * 4 + tw;
    float v = w[(size_t)(r0 + r) * N_DIM + c0 + tc];
    s = fmaf(v, v, s);
    tile[tc][r] = f2bf(v);
  }
  atomicAdd(&cn[c0 + tc], s);
  __syncthreads();
  int cc = threadIdx.x >> 4;        // 0..15
  int rr = (threadIdx.x & 15) * 4;  // 0..60
#pragma unroll
  for (int i = 0; i < 4; ++i) {
    int c = cc + i * 16;
    ushort4 v = *(const ushort4*)&tile[c][rr];
    *(ushort4*)(wT + (size_t)(c0 + c) * K_DIM + r0 + rr) = v;
  }
}

// ---------------- Kernel 3: 256x256 GEMM, K-half ring buffers + counted vmcnt ----------------
// C[M][N] = xn[M][K] * wT[N][K]^T * rsqrt(cn[N]), bf16 MFMA, fp32 out.
// LDS: per matrix 4 half-slots of 16 KiB ([256 rows][32 kk], XOR-swizzled k8);
// slot(kt,h) = (2kt+h)&3. Stage 1 half/phase; vmcnt(8) at phases 2,4 only.
__global__ __launch_bounds__(512, 2) void k_gemm(const u16* __restrict__ A,
                                                 const u16* __restrict__ Bt,
                                                 const float* __restrict__ cn,
                                                 float* __restrict__ C) {
  __shared__ u16 sm[65536];  // 128 KiB: A slots [0..4)*8192, B at 32768 + slot*8192

  // XCD swizzle: 4000 % 8 == 0 -> bijective
  int bid = blockIdx.x;
  bid = (bid & 7) * 500 + (bid >> 3);
  const int bm = bid / 125;
  const int bn = bid % 125;

  const int tid = threadIdx.x;
  const int lane = tid & 63;
  const int w = tid >> 6;   // 0..7
  const int wr = w >> 2;    // 0..1
  const int wc = w & 3;     // 0..3
  const int la = lane & 15;
  const int lk = lane >> 4; // 0..3
  const int swz = lk ^ ((la >> 1) & 3);
  const int aoff = (wr * 128 + la) * 32 + swz * 8;  // elems within A slot; +m*512
  const int boff = (wc * 64 + la) * 32 + swz * 8;   // elems within B slot; +n*512

  // staging: instr i covers rows i*128 + (tid>>2); lane's 16B at logical k8 =
  // (tid&3) ^ ((tid>>3)&3) so the LINEAR LDS dest is swizzle-stored (rule #21).
  const int sgswz = ((tid & 3) ^ ((tid >> 3) & 3)) * 8;
  const u16* agp = A  + (size_t)(bm * 256 + (tid >> 2)) * K_DIM + sgswz;
  const u16* bgp = Bt + (size_t)(bn * 256 + (tid >> 2)) * K_DIM + sgswz;
  const int d0 = tid * 8;  // lds elem offset within half-slot (instr 0); +4096 for instr 1

#define GLLA(koff, eoff)                                                          \
  __builtin_amdgcn_global_load_lds(                                              \
      (const __attribute__((address_space(1))) void*)(agp + (koff)),             \
      (__attribute__((address_space(3))) void*)&sm[(eoff)], 16, 0, 0)
#define GLLB(koff, eoff)                                                          \
  __builtin_amdgcn_global_load_lds(                                              \
      (const __attribute__((address_space(1))) void*)(bgp + (koff)),             \
      (__attribute__((address_space(3))) void*)&sm[(eoff)], 16, 0, 0)
// stage A half (tile t, half h) -> slot s   (2 loads, rows 0-127 / 128-255)
#define STAGE_A(t, h, s)                                                          \
  { GLLA((t)*64 + (h)*32,           (s)*8192 + d0);                               \
    GLLA((t)*64 + (h)*32 + 65536,   (s)*8192 + 4096 + d0); }
#define STAGE_B(t, h, s)                                                          \
  { GLLB((t)*64 + (h)*32,           32768 + (s)*8192 + d0);                       \
    GLLB((t)*64 + (h)*32 + 65536,   32768 + (s)*8192 + 4096 + d0); }

  f32x4 acc[8][4] = {};

  // ---- prologue: A00 B00 A01 B01 A10 B10 ; wait oldest 2 halves ----
  STAGE_A(0, 0, 0); STAGE_B(0, 0, 0);
  STAGE_A(0, 1, 1); STAGE_B(0, 1, 1);
  STAGE_A(1, 0, 2); STAGE_B(1, 0, 2);
  asm volatile("s_waitcnt vmcnt(8)" ::: "memory");
  __builtin_amdgcn_s_barrier();
  __builtin_amdgcn_sched_barrier(0);

#pragma unroll
  for (int kt = 0; kt < 8; ++kt) {
    const int sA0 = (2 * kt) & 3;      // this tile's kk-half0 slot (A and B)
    const int sA1 = (2 * kt + 1) & 3;  // kk-half1 slot
    const int sT1 = (2 * kt + 3) & 3;  // stage slot for (kt+1, half1)
    const int sT2 = (2 * kt + 4) & 3;  // stage slot for (kt+2, half0)
    const int t1 = (kt + 1 < 8) ? kt + 1 : 7;  // clamped src (garbage lands in dead slot)
    const int t2 = (kt + 2 < 8) ? kt + 2 : 7;

    bf16x8 bfr[4], af[4];

    // ---- phase 1: stage A(kt+1,1); read B(kt,h0) + A(kt,h0,m0-3); MFMA kk0 m0-3 ----
    STAGE_A(t1, 1, sT1);
#pragma unroll
    for (int n = 0; n < 4; ++n)
      bfr[n] = *(const bf16x8*)&sm[32768 + sA0 * 8192 + boff + n * 512];
#pragma unroll
    for (int m = 0; m < 4; ++m)
      af[m] = *(const bf16x8*)&sm[sA0 * 8192 + aoff + m * 512];
    __builtin_amdgcn_s_barrier();
    asm volatile("s_waitcnt lgkmcnt(0)" ::: "memory");
    __builtin_amdgcn_sched_barrier(0);
    __builtin_amdgcn_s_setprio(1);
#pragma unroll
    for (int m = 0; m < 4; ++m)
#pragma unroll
      for (int n = 0; n < 4; ++n)
        acc[m][n] = __builtin_amdgcn_mfma_f32_16x16x32_bf16(af[m], bfr[n], acc[m][n], 0, 0, 0);
    __builtin_amdgcn_s_setprio(0);
    __builtin_amdgcn_s_barrier();
    __builtin_amdgcn_sched_barrier(0);

    // ---- phase 2: stage B(kt+1,1); read A(kt,h0,m4-7); vmcnt(8); MFMA kk0 m4-7 ----
    STAGE_B(t1, 1, sT1);
#pragma unroll
    for (int m = 0; m < 4; ++m)
      af[m] = *(const bf16x8*)&sm[sA0 * 8192 + aoff + (4 + m) * 512];
    asm volatile("s_waitcnt vmcnt(8)" ::: "memory");
    __builtin_amdgcn_s_barrier();
    asm volatile("s_waitcnt lgkmcnt(0)" ::: "memory");
    __builtin_amdgcn_sched_barrier(0);
    __builtin_amdgcn_s_setprio(1);
#pragma unroll
    for (int m = 0; m < 4; ++m)
#pragma unroll
      for (int n = 0; n < 4; ++n)
        acc[4 + m][n] = __builtin_amdgcn_mfma_f32_16x16x32_bf16(af[m], bfr[n], acc[4 + m][n], 0, 0, 0);
    __builtin_amdgcn_s_setprio(0);
    __builtin_amdgcn_s_barrier();
    __builtin_amdgcn_sched_barrier(0);

    // ---- phase 3: stage A(kt+2,0); read B(kt,h1) + A(kt,h1,m0-3); MFMA kk1 m0-3 ----
    STAGE_A(t2, 0, sT2);
#pragma unroll
    for (int n = 0; n < 4; ++n)
      bfr[n] = *(const bf16x8*)&sm[32768 + sA1 * 8192 + boff + n * 512];
#pragma unroll
    for (int m = 0; m < 4; ++m)
      af[m] = *(const bf16x8*)&sm[sA1 * 8192 + aoff + m * 512];
    __builtin_amdgcn_s_barrier();
    asm volatile("s_waitcnt lgkmcnt(0)" ::: "memory");
    __builtin_amdgcn_sched_barrier(0);
    __builtin_amdgcn_s_setprio(1);
#pragma unroll
    for (int m = 0; m < 4; ++m)
#pragma unroll
      for (int n = 0; n < 4; ++n)
        acc[m][n] = __builtin_amdgcn_mfma_f32_16x16x32_bf16(af[m], bfr[n], acc[m][n], 0, 0, 0);
    __builtin_amdgcn_s_setprio(0);
    __builtin_amdgcn_s_barrier();
    __builtin_amdgcn_sched_barrier(0);

    // ---- phase 4: stage B(kt+2,0); read A(kt,h1,m4-7); vmcnt(8); MFMA kk1 m4-7 ----
    STAGE_B(t2, 0, sT2);
#pragma unroll
    for (int m = 0; m < 4; ++m)
      af[m] = *(const bf16x8*)&sm[sA1 * 8192 + aoff + (4 + m) * 512];
    asm volatile("s_waitcnt vmcnt(8)" ::: "memory");
    __builtin_amdgcn_s_barrier();
    asm volatile("s_waitcnt lgkmcnt(0)" ::: "memory");
    __builtin_amdgcn_sched_barrier(0);
    __builtin_amdgcn_s_setprio(1);
#pragma unroll
    for (int m = 0; m < 4; ++m)
#pragma unroll
      for (int n = 0; n < 4; ++n)
        acc[4 + m][n] = __builtin_amdgcn_mfma_f32_16x16x32_bf16(af[m], bfr[n], acc[4 + m][n], 0, 0, 0);
    __builtin_amdgcn_s_setprio(0);
    __builtin_amdgcn_s_barrier();
    __builtin_amdgcn_sched_barrier(0);
  }

  // ---- epilogue: drain garbage stages, scale by rsqrt(col sumsq), store ----
  asm volatile("s_waitcnt vmcnt(0)" ::: "memory");
  const size_t crow0 = (size_t)bm * 256 + wr * 128 + lk * 4;
  const int ccol0 = bn * 256 + wc * 64 + la;
  float rs[4];
#pragma unroll
  for (int n = 0; n < 4; ++n)
    rs[n] = rsqrtf(fmaxf(cn[ccol0 + n * 16], 1e-12f));
#pragma unroll
  for (int m = 0; m < 8; ++m)
#pragma unroll
    for (int j = 0; j < 4; ++j) {
      float* cp = C + (crow0 + m * 16 + j) * N_DIM + ccol0;
#pragma unroll
      for (int n = 0; n < 4; ++n)
        __builtin_nontemporal_store(acc[m][n][j] * rs[n], cp + n * 16);
    }
#undef GLLA
#undef GLLB
#undef STAGE_A
#undef STAGE_B
}

// ---------------- launch ----------------
extern "C" void kernel_launch(void* const* d_in, const int* in_sizes, int n_in,
                              void* d_out, int out_size, void* d_ws, size_t ws_size,
                              hipStream_t stream) {
  const float* x = (const float*)d_in[0];   // [8192, 512]
  const float* w = (const float*)d_in[1];   // [512, 32000]
  float* out = (float*)d_out;               // [8192, 32000]

  char* ws = (char*)d_ws;
  float* cn = (float*)ws;                                    // 32000 f32 (sumsq)
  u16* xn = (u16*)(ws + 131072);                             // 8192*512 bf16
  u16* wT = (u16*)(ws + 131072 + (size_t)M_DIM * K_DIM * 2); // 32000*512 bf16

  k_zero<<<N_DIM / 256, 256, 0, stream>>>(cn);
  k_xnorm<<<M_DIM / 4, 256, 0, stream>>>(x, xn);
  k_wtrans<<<dim3(N_DIM / 64, K_DIM / 64), 256, 0, stream>>>(w, cn, wT);
  k_gemm<<<(M_DIM / 256) * (N_DIM / 256), 512, 0, stream>>>(xn, wT, cn, out);
}

// Round 7
// 420.929 us; speedup vs baseline: 1.2253x; 1.0292x over previous
//
#include <hip/hip_runtime.h>
#include <hip/hip_bf16.h>
#include <stdint.h>

#define M_DIM 8192
#define K_DIM 512
#define N_DIM 32000
#define NTILES 4000   // 32 * 125
#define NBLK 256

typedef short bf16x8 __attribute__((ext_vector_type(8)));
typedef float f32x4 __attribute__((ext_vector_type(4)));
typedef unsigned short u16;

__device__ __forceinline__ u16 f2bf(float f) {
  union { float f; uint32_t u; } v; v.f = f;
  uint32_t r = (v.u + 0x7fffu + ((v.u >> 16) & 1u)) >> 16;  // RNE
  return (u16)r;
}

// ---------------- Kernel 0: zero the column-sumsq accumulator ----------------
__global__ void k_zero(float* __restrict__ cn) {
  cn[blockIdx.x * 256 + threadIdx.x] = 0.f;
}

// ---------------- Kernel 1: row-l2norm of x -> bf16, one wave per row ----------------
__global__ void k_xnorm(const float* __restrict__ x, u16* __restrict__ xn) {
  int row = (blockIdx.x * blockDim.x + threadIdx.x) >> 6;
  int lane = threadIdx.x & 63;
  const float4* rp = (const float4*)(x + (size_t)row * K_DIM);
  float4 a = rp[lane];
  float4 b = rp[lane + 64];
  float s = a.x*a.x + a.y*a.y + a.z*a.z + a.w*a.w
          + b.x*b.x + b.y*b.y + b.z*b.z + b.w*b.w;
#pragma unroll
  for (int off = 32; off > 0; off >>= 1) s += __shfl_xor(s, off, 64);
  float r = rsqrtf(fmaxf(s, 1e-12f));
  ushort4 o0 = make_ushort4(f2bf(a.x*r), f2bf(a.y*r), f2bf(a.z*r), f2bf(a.w*r));
  ushort4 o1 = make_ushort4(f2bf(b.x*r), f2bf(b.y*r), f2bf(b.z*r), f2bf(b.w*r));
  ushort4* dst = (ushort4*)(xn + (size_t)row * K_DIM);
  dst[lane] = o0;
  dst[lane + 64] = o1;
}

// ---------------- Kernel 2: transpose + cast (UNNORMALIZED) + fused col-sumsq ----------------
__global__ void k_wtrans(const float* __restrict__ w, float* __restrict__ cn,
                         u16* __restrict__ wT) {
  __shared__ u16 tile[64][68];
  int c0 = blockIdx.x * 64;
  int r0 = blockIdx.y * 64;
  int tc = threadIdx.x & 63;
  int tw = threadIdx.x >> 6;  // 0..3
  float s = 0.f;
#pragma unroll
  for (int i = 0; i < 16; ++i) {
    int r = i * 4 + tw;
    float v = w[(size_t)(r0 + r) * N_DIM + c0 + tc];
    s = fmaf(v, v, s);
    tile[tc][r] = f2bf(v);
  }
  atomicAdd(&cn[c0 + tc], s);
  __syncthreads();
  int cc = threadIdx.x >> 4;        // 0..15
  int rr = (threadIdx.x & 15) * 4;  // 0..60
#pragma unroll
  for (int i = 0; i < 4; ++i) {
    int c = cc + i * 16;
    ushort4 v = *(const ushort4*)&tile[c][rr];
    *(ushort4*)(wT + (size_t)(c0 + c) * K_DIM + r0 + rr) = v;
  }
}

// ---------------- Kernel 3: PERSISTENT grid-stride 256x256 GEMM, K-half ring + counted vmcnt ----
// Block b processes tiles seq = b, b+256, ... < 4000 (grid-stride keeps the
// launched-grid locality pattern). Ring pipeline stages seamlessly across tile
// boundaries (16 halves/tile == 0 mod 4 keeps slot arithmetic aligned).
__global__ __launch_bounds__(512, 2) void k_gemm(const u16* __restrict__ A,
                                                 const u16* __restrict__ Bt,
                                                 const float* __restrict__ cn,
                                                 float* __restrict__ C) {
  __shared__ u16 sm[65536];  // A slots [0..4)*8192, B at 32768 + slot*8192

  const int b = blockIdx.x;
  const int tid = threadIdx.x;
  const int lane = tid & 63;
  const int w = tid >> 6;   // 0..7
  const int wr = w >> 2;    // 0..1
  const int wc = w & 3;     // 0..3
  const int la = lane & 15;
  const int lk = lane >> 4; // 0..3
  const int swz = lk ^ ((la >> 1) & 3);
  const int aoff = (wr * 128 + la) * 32 + swz * 8;  // + m*512
  const int boff = (wc * 64 + la) * 32 + swz * 8;   // + n*512

  // staging: instr covers rows r0 + (tid>>2); lane's 16B at logical k8 =
  // (tid&3) ^ ((tid>>3)&3) so the LINEAR LDS dest is swizzle-stored (rule #21)
  const int sgswz = ((tid & 3) ^ ((tid >> 3) & 3)) * 8;
  const int srow = tid >> 2;
  const int d0 = tid * 8;

#define GLL(p, eoff)                                                              \
  __builtin_amdgcn_global_load_lds(                                              \
      (const __attribute__((address_space(1))) void*)(p),                        \
      (__attribute__((address_space(3))) void*)&sm[(eoff)], 16, 0, 0)
#define STAGE_A(p, s) { GLL((p), (s)*8192 + d0); GLL((p) + 65536, (s)*8192 + 4096 + d0); }
#define STAGE_B(p, s) { GLL((p), 32768 + (s)*8192 + d0); GLL((p) + 65536, 32768 + (s)*8192 + 4096 + d0); }

  int seq = b;
  int bid = (seq & 7) * 500 + (seq >> 3);
  int bm = bid / 125, bn = bid % 125;
  const u16* ag = A  + (size_t)(bm * 256 + srow) * K_DIM + sgswz;
  const u16* bg = Bt + (size_t)(bn * 256 + srow) * K_DIM + sgswz;

  f32x4 acc[8][4] = {};

  // prologue: stage halves (0,0)->s0, (0,1)->s1, (1,0)->s2
  STAGE_A(ag, 0);       STAGE_B(bg, 0);
  STAGE_A(ag + 32, 1);  STAGE_B(bg + 32, 1);
  STAGE_A(ag + 64, 2);  STAGE_B(bg + 64, 2);
  asm volatile("s_waitcnt vmcnt(8)" ::: "memory");
  __builtin_amdgcn_s_barrier();

  for (int ti = 0;; ++ti) {
    const int seqn = seq + NBLK;
    const bool last = (seqn >= NTILES);
    int bmn = bm, bnn = bn;
    if (!last) {
      int bidn = (seqn & 7) * 500 + (seqn >> 3);
      bmn = bidn / 125; bnn = bidn % 125;
    }
    const u16* agn = A  + (size_t)(bmn * 256 + srow) * K_DIM + sgswz;
    const u16* bgn = Bt + (size_t)(bnn * 256 + srow) * K_DIM + sgswz;

#pragma unroll
    for (int kt = 0; kt < 8; ++kt) {
      const int sA0 = (2 * kt) & 3;
      const int sA1 = (2 * kt + 1) & 3;
      const int sT1 = (2 * kt + 3) & 3;   // gets (kt+1, h1)  [kt==7 -> next tile (0,h1)]
      const int sT2 = (2 * kt + 4) & 3;   // gets (kt+2, h0)  [kt==6 -> next (0,h0); kt==7 -> next (1,h0)]
      const u16* a1 = (kt < 7) ? (ag + (kt + 1) * 64 + 32) : (agn + 32);
      const u16* b1 = (kt < 7) ? (bg + (kt + 1) * 64 + 32) : (bgn + 32);
      const u16* a2 = (kt < 6) ? (ag + (kt + 2) * 64) : ((kt == 6) ? agn : (agn + 64));
      const u16* b2 = (kt < 6) ? (bg + (kt + 2) * 64) : ((kt == 6) ? bgn : (bgn + 64));

      bf16x8 bfr[4], af[4];

      // ---- phase 1: stage A->sT1; read B(h0), A(h0,m0-3); MFMA ----
      STAGE_A(a1, sT1);
#pragma unroll
      for (int n = 0; n < 4; ++n)
        bfr[n] = *(const bf16x8*)&sm[32768 + sA0 * 8192 + boff + n * 512];
#pragma unroll
      for (int m = 0; m < 4; ++m)
        af[m] = *(const bf16x8*)&sm[sA0 * 8192 + aoff + m * 512];
      __builtin_amdgcn_s_barrier();
      __builtin_amdgcn_s_setprio(1);
#pragma unroll
      for (int m = 0; m < 4; ++m)
#pragma unroll
        for (int n = 0; n < 4; ++n)
          acc[m][n] = __builtin_amdgcn_mfma_f32_16x16x32_bf16(af[m], bfr[n], acc[m][n], 0, 0, 0);
      __builtin_amdgcn_s_setprio(0);
      __builtin_amdgcn_s_barrier();

      // ---- phase 2: stage B->sT1; read A(h0,m4-7); vmcnt(8); MFMA ----
      STAGE_B(b1, sT1);
#pragma unroll
      for (int m = 0; m < 4; ++m)
        af[m] = *(const bf16x8*)&sm[sA0 * 8192 + aoff + (4 + m) * 512];
      asm volatile("s_waitcnt vmcnt(8)" ::: "memory");
      __builtin_amdgcn_s_barrier();
      __builtin_amdgcn_s_setprio(1);
#pragma unroll
      for (int m = 0; m < 4; ++m)
#pragma unroll
        for (int n = 0; n < 4; ++n)
          acc[4 + m][n] = __builtin_amdgcn_mfma_f32_16x16x32_bf16(af[m], bfr[n], acc[4 + m][n], 0, 0, 0);
      __builtin_amdgcn_s_setprio(0);
      __builtin_amdgcn_s_barrier();

      // ---- phase 3: stage A->sT2; read B(h1), A(h1,m0-3); MFMA ----
      STAGE_A(a2, sT2);
#pragma unroll
      for (int n = 0; n < 4; ++n)
        bfr[n] = *(const bf16x8*)&sm[32768 + sA1 * 8192 + boff + n * 512];
#pragma unroll
      for (int m = 0; m < 4; ++m)
        af[m] = *(const bf16x8*)&sm[sA1 * 8192 + aoff + m * 512];
      __builtin_amdgcn_s_barrier();
      __builtin_amdgcn_s_setprio(1);
#pragma unroll
      for (int m = 0; m < 4; ++m)
#pragma unroll
        for (int n = 0; n < 4; ++n)
          acc[m][n] = __builtin_amdgcn_mfma_f32_16x16x32_bf16(af[m], bfr[n], acc[m][n], 0, 0, 0);
      __builtin_amdgcn_s_setprio(0);
      __builtin_amdgcn_s_barrier();

      // ---- phase 4: stage B->sT2; read A(h1,m4-7); vmcnt(8); MFMA ----
      STAGE_B(b2, sT2);
#pragma unroll
      for (int m = 0; m < 4; ++m)
        af[m] = *(const bf16x8*)&sm[sA1 * 8192 + aoff + (4 + m) * 512];
      asm volatile("s_waitcnt vmcnt(8)" ::: "memory");
      __builtin_amdgcn_s_barrier();
      __builtin_amdgcn_s_setprio(1);
#pragma unroll
      for (int m = 0; m < 4; ++m)
#pragma unroll
        for (int n = 0; n < 4; ++n)
          acc[4 + m][n] = __builtin_amdgcn_mfma_f32_16x16x32_bf16(af[m], bfr[n], acc[4 + m][n], 0, 0, 0);
      __builtin_amdgcn_s_setprio(0);
      __builtin_amdgcn_s_barrier();
    }

    // ---- tile epilogue: scale by rsqrt(col sumsq), fire-and-forget stores ----
    {
      const size_t crow0 = (size_t)bm * 256 + wr * 128 + lk * 4;
      const int ccol0 = bn * 256 + wc * 64 + la;
      float rs[4];
#pragma unroll
      for (int n = 0; n < 4; ++n)
        rs[n] = rsqrtf(fmaxf(cn[ccol0 + n * 16], 1e-12f));
#pragma unroll
      for (int m = 0; m < 8; ++m)
#pragma unroll
        for (int j = 0; j < 4; ++j) {
          float* cp = C + (crow0 + m * 16 + j) * N_DIM + ccol0;
#pragma unroll
          for (int n = 0; n < 4; ++n)
            __builtin_nontemporal_store(acc[m][n][j] * rs[n], cp + n * 16);
        }
#pragma unroll
      for (int m = 0; m < 8; ++m)
#pragma unroll
        for (int n = 0; n < 4; ++n)
          acc[m][n] = (f32x4){0.f, 0.f, 0.f, 0.f};
    }

    if (last) break;
    seq = seqn; bm = bmn; bn = bnn; ag = agn; bg = bgn;
  }
#undef GLL
#undef STAGE_A
#undef STAGE_B
}

// ---------------- launch ----------------
extern "C" void kernel_launch(void* const* d_in, const int* in_sizes, int n_in,
                              void* d_out, int out_size, void* d_ws, size_t ws_size,
                              hipStream_t stream) {
  const float* x = (const float*)d_in[0];   // [8192, 512]
  const float* w = (const float*)d_in[1];   // [512, 32000]
  float* out = (float*)d_out;               // [8192, 32000]

  char* ws = (char*)d_ws;
  float* cn = (float*)ws;                                    // 32000 f32 (sumsq)
  u16* xn = (u16*)(ws + 131072);                             // 8192*512 bf16
  u16* wT = (u16*)(ws + 131072 + (size_t)M_DIM * K_DIM * 2); // 32000*512 bf16

  k_zero<<<N_DIM / 256, 256, 0, stream>>>(cn);
  k_xnorm<<<M_DIM / 4, 256, 0, stream>>>(x, xn);
  k_wtrans<<<dim3(N_DIM / 64, K_DIM / 64), 256, 0, stream>>>(w, cn, wT);
  k_gemm<<<NBLK, 512, 0, stream>>>(xn, wT, cn, out);
}

// Round 8
// 375.158 us; speedup vs baseline: 1.3748x; 1.1220x over previous
//
#include <hip/hip_runtime.h>
#include <hip/hip_bf16.h>
#include <stdint.h>

#define M_DIM 8192
#define K_DIM 512
#define N_DIM 32000

typedef short bf16x8 __attribute__((ext_vector_type(8)));
typedef float f32x4 __attribute__((ext_vector_type(4)));
typedef unsigned short u16;

__device__ __forceinline__ u16 f2bf(float f) {
  union { float f; uint32_t u; } v; v.f = f;
  uint32_t r = (v.u + 0x7fffu + ((v.u >> 16) & 1u)) >> 16;  // RNE
  return (u16)r;
}

// ---------------- Kernel 0: zero the column-sumsq accumulator ----------------
__global__ void k_zero(float* __restrict__ cn) {
  cn[blockIdx.x * 256 + threadIdx.x] = 0.f;
}

// ---------------- Kernel 1: row-l2norm of x -> bf16, one wave per row ----------------
__global__ void k_xnorm(const float* __restrict__ x, u16* __restrict__ xn) {
  int row = (blockIdx.x * blockDim.x + threadIdx.x) >> 6;
  int lane = threadIdx.x & 63;
  const float4* rp = (const float4*)(x + (size_t)row * K_DIM);
  float4 a = rp[lane];
  float4 b = rp[lane + 64];
  float s = a.x*a.x + a.y*a.y + a.z*a.z + a.w*a.w
          + b.x*b.x + b.y*b.y + b.z*b.z + b.w*b.w;
#pragma unroll
  for (int off = 32; off > 0; off >>= 1) s += __shfl_xor(s, off, 64);
  float r = rsqrtf(fmaxf(s, 1e-12f));
  ushort4 o0 = make_ushort4(f2bf(a.x*r), f2bf(a.y*r), f2bf(a.z*r), f2bf(a.w*r));
  ushort4 o1 = make_ushort4(f2bf(b.x*r), f2bf(b.y*r), f2bf(b.z*r), f2bf(b.w*r));
  ushort4* dst = (ushort4*)(xn + (size_t)row * K_DIM);
  dst[lane] = o0;
  dst[lane + 64] = o1;
}

// ---------------- Kernel 2: transpose + cast (UNNORMALIZED) + fused col-sumsq ----------------
__global__ void k_wtrans(const float* __restrict__ w, float* __restrict__ cn,
                         u16* __restrict__ wT) {
  __shared__ u16 tile[64][68];
  int c0 = blockIdx.x * 64;
  int r0 = blockIdx.y * 64;
  int tc = threadIdx.x & 63;
  int tw = threadIdx.x >> 6;  // 0..3
  float s = 0.f;
#pragma unroll
  for (int i = 0; i < 16; ++i) {
    int r = i * 4 + tw;
    float v = w[(size_t)(r0 + r) * N_DIM + c0 + tc];
    s = fmaf(v, v, s);
    tile[tc][r] = f2bf(v);
  }
  atomicAdd(&cn[c0 + tc], s);
  __syncthreads();
  int cc = threadIdx.x >> 4;        // 0..15
  int rr = (threadIdx.x & 15) * 4;  // 0..60
#pragma unroll
  for (int i = 0; i < 4; ++i) {
    int c = cc + i * 16;
    ushort4 v = *(const ushort4*)&tile[c][rr];
    *(ushort4*)(wT + (size_t)(c0 + c) * K_DIM + r0 + rr) = v;
  }
}

// ---------------- Kernel 3: PERSISTENT XCD-BANDED 256x256 GEMM (R2 K-loop) ----------------
// 256 blocks = 1/CU. XCD (b&7) owns bm band [xcd*4, xcd*4+4) -> A slice (1 MB)
// L2-resident. CU keeps bm FIXED, walks bn = bn0, bn0+8, ... so each XCD's 32
// CUs touch 8 B tiles (2.1 MB) at a time -> B streams through L2 once per XCD.
__global__ __launch_bounds__(512, 2) void k_gemm(const u16* __restrict__ A,
                                                 const u16* __restrict__ Bt,
                                                 const float* __restrict__ cn,
                                                 float* __restrict__ C) {
  __shared__ u16 sm[2][32768];  // per buf: A [256][64] @0, B [256][64] @16384
  constexpr int BOFF = 16384;

  const int b = blockIdx.x;
  const int xcd = b & 7;        // dispatch round-robins XCDs by blockIdx
  const int cu = b >> 3;        // 0..31 within XCD
  const int bm = xcd * 4 + (cu & 3);   // FIXED per CU, all run
  const int bn0 = cu >> 2;             // 0..7
  const int cnt = (bn0 < 5) ? 16 : 15; // bn = bn0 + 8*ti < 125

  const int tid = threadIdx.x;
  const int lane = tid & 63;
  const int w = tid >> 6;   // 0..7
  const int wr = w >> 2;    // 0..1
  const int wc = w & 3;     // 0..3
  const int la = lane & 15;
  const int lk = lane >> 4;
  const int rx = la & 7;
  const int s0 = ((0 + lk) ^ rx) * 8;  // swizzled elem-col, kk=0
  const int s1 = ((4 + lk) ^ rx) * 8;  // swizzled elem-col, kk=32

  // staging (rule #21: linear LDS dest + inverse-swizzled global src)
  const int srow = tid >> 3;
  const int sgl = ((tid & 7) ^ (srow & 7)) * 8;
  const int ldst = srow * 64 + (tid & 7) * 8;
  const int arow0 = (wr * 128 + la) * 64;
  const int brow0 = (wc * 64 + la) * 64;

  const u16* ag = A + (size_t)(bm * 256 + srow) * K_DIM + sgl;  // fixed
  int bn = bn0;
  const u16* bg = Bt + (size_t)(bn * 256 + srow) * K_DIM + sgl;
  constexpr size_t BSTEP = (size_t)8 * 256 * K_DIM;  // bn += 8

  f32x4 acc[8][4] = {};

  // prologue: stage (tile0, kt=0) into buf 0
#pragma unroll
  for (int i = 0; i < 4; ++i)
    __builtin_amdgcn_global_load_lds(
        (const __attribute__((address_space(1))) void*)(ag + (size_t)i * 64 * K_DIM),
        (__attribute__((address_space(3))) void*)&sm[0][i * 4096 + ldst], 16, 0, 0);
#pragma unroll
  for (int i = 0; i < 4; ++i)
    __builtin_amdgcn_global_load_lds(
        (const __attribute__((address_space(1))) void*)(bg + (size_t)i * 64 * K_DIM),
        (__attribute__((address_space(3))) void*)&sm[0][BOFF + i * 4096 + ldst], 16, 0, 0);
  __syncthreads();

  for (int ti = 0; ti < cnt; ++ti) {
    const bool last_tile = (ti + 1 == cnt);

    for (int kt = 0; kt < 8; ++kt) {
      const int cur = kt & 1;
      const int nxt = cur ^ 1;
      const bool pf = (kt < 7) || !last_tile;
      const u16* agk = (kt < 7) ? (ag + (kt + 1) * 64) : ag;           // next tile: same A panel
      const u16* bgk = (kt < 7) ? (bg + (kt + 1) * 64) : (bg + BSTEP); // next tile: bn+8

      bf16x8 bf[4][2];

      // ---- phase 1: m = 0,1 ; read all B frags; stage next A ----
      {
#pragma unroll
        for (int n = 0; n < 4; ++n) {
          bf[n][0] = *(const bf16x8*)&sm[cur][BOFF + brow0 + n * 1024 + s0];
          bf[n][1] = *(const bf16x8*)&sm[cur][BOFF + brow0 + n * 1024 + s1];
        }
        bf16x8 af[2][2];
#pragma unroll
        for (int m = 0; m < 2; ++m) {
          af[m][0] = *(const bf16x8*)&sm[cur][arow0 + m * 1024 + s0];
          af[m][1] = *(const bf16x8*)&sm[cur][arow0 + m * 1024 + s1];
        }
        if (pf) {
#pragma unroll
          for (int i = 0; i < 4; ++i)
            __builtin_amdgcn_global_load_lds(
                (const __attribute__((address_space(1))) void*)(agk + (size_t)i * 64 * K_DIM),
                (__attribute__((address_space(3))) void*)&sm[nxt][i * 4096 + ldst], 16, 0, 0);
        }
        __builtin_amdgcn_s_barrier();
        asm volatile("s_waitcnt lgkmcnt(0)" ::: "memory");
        __builtin_amdgcn_sched_barrier(0);
        __builtin_amdgcn_s_setprio(1);
#pragma unroll
        for (int m = 0; m < 2; ++m)
#pragma unroll
          for (int n = 0; n < 4; ++n) {
            acc[m][n] = __builtin_amdgcn_mfma_f32_16x16x32_bf16(af[m][0], bf[n][0], acc[m][n], 0, 0, 0);
            acc[m][n] = __builtin_amdgcn_mfma_f32_16x16x32_bf16(af[m][1], bf[n][1], acc[m][n], 0, 0, 0);
          }
        __builtin_amdgcn_s_setprio(0);
        __builtin_amdgcn_s_barrier();
      }

      // ---- phases 2..4: m = 2p..2p+1 ; phase 2 stages next B ----
#pragma unroll
      for (int p = 1; p < 4; ++p) {
        bf16x8 af[2][2];
#pragma unroll
        for (int m = 0; m < 2; ++m) {
          af[m][0] = *(const bf16x8*)&sm[cur][arow0 + (p * 2 + m) * 1024 + s0];
          af[m][1] = *(const bf16x8*)&sm[cur][arow0 + (p * 2 + m) * 1024 + s1];
        }
        if (p == 1 && pf) {
#pragma unroll
          for (int i = 0; i < 4; ++i)
            __builtin_amdgcn_global_load_lds(
                (const __attribute__((address_space(1))) void*)(bgk + (size_t)i * 64 * K_DIM),
                (__attribute__((address_space(3))) void*)&sm[nxt][BOFF + i * 4096 + ldst], 16, 0, 0);
        }
        __builtin_amdgcn_s_barrier();
        asm volatile("s_waitcnt lgkmcnt(0)" ::: "memory");
        __builtin_amdgcn_sched_barrier(0);
        __builtin_amdgcn_s_setprio(1);
#pragma unroll
        for (int m = 0; m < 2; ++m)
#pragma unroll
          for (int n = 0; n < 4; ++n) {
            acc[p * 2 + m][n] = __builtin_amdgcn_mfma_f32_16x16x32_bf16(af[m][0], bf[n][0], acc[p * 2 + m][n], 0, 0, 0);
            acc[p * 2 + m][n] = __builtin_amdgcn_mfma_f32_16x16x32_bf16(af[m][1], bf[n][1], acc[p * 2 + m][n], 0, 0, 0);
          }
        __builtin_amdgcn_s_setprio(0);
        if (p < 3) __builtin_amdgcn_s_barrier();
      }

      __syncthreads();  // drains staging (and any in-flight epilogue stores)
    }

    // ---- tile epilogue: scale by rsqrt(col sumsq), fire-and-forget stores ----
    {
      const size_t crow0 = (size_t)bm * 256 + wr * 128 + lk * 4;
      const int ccol0 = bn * 256 + wc * 64 + la;
      float rs[4];
#pragma unroll
      for (int n = 0; n < 4; ++n)
        rs[n] = rsqrtf(fmaxf(cn[ccol0 + n * 16], 1e-12f));
#pragma unroll
      for (int m = 0; m < 8; ++m)
#pragma unroll
        for (int j = 0; j < 4; ++j) {
          float* cp = C + (crow0 + m * 16 + j) * N_DIM + ccol0;
#pragma unroll
          for (int n = 0; n < 4; ++n)
            __builtin_nontemporal_store(acc[m][n][j] * rs[n], cp + n * 16);
        }
#pragma unroll
      for (int m = 0; m < 8; ++m)
#pragma unroll
        for (int n = 0; n < 4; ++n)
          acc[m][n] = (f32x4){0.f, 0.f, 0.f, 0.f};
    }

    bn += 8;
    bg += BSTEP;
  }
}

// ---------------- launch ----------------
extern "C" void kernel_launch(void* const* d_in, const int* in_sizes, int n_in,
                              void* d_out, int out_size, void* d_ws, size_t ws_size,
                              hipStream_t stream) {
  const float* x = (const float*)d_in[0];   // [8192, 512]
  const float* w = (const float*)d_in[1];   // [512, 32000]
  float* out = (float*)d_out;               // [8192, 32000]

  char* ws = (char*)d_ws;
  float* cn = (float*)ws;                                    // 32000 f32 (sumsq)
  u16* xn = (u16*)(ws + 131072);                             // 8192*512 bf16
  u16* wT = (u16*)(ws + 131072 + (size_t)M_DIM * K_DIM * 2); // 32000*512 bf16

  k_zero<<<N_DIM / 256, 256, 0, stream>>>(cn);
  k_xnorm<<<M_DIM / 4, 256, 0, stream>>>(x, xn);
  k_wtrans<<<dim3(N_DIM / 64, K_DIM / 64), 256, 0, stream>>>(w, cn, wT);
  k_gemm<<<256, 512, 0, stream>>>(xn, wT, cn, out);
}

// Round 9
// 355.847 us; speedup vs baseline: 1.4494x; 1.0543x over previous
//
#include <hip/hip_runtime.h>
#include <hip/hip_bf16.h>
#include <stdint.h>

#define M_DIM 8192
#define K_DIM 512
#define N_DIM 32000

typedef short bf16x8 __attribute__((ext_vector_type(8)));
typedef float f32x4 __attribute__((ext_vector_type(4)));
typedef unsigned short u16;

__device__ __forceinline__ u16 f2bf(float f) {
  union { float f; uint32_t u; } v; v.f = f;
  uint32_t r = (v.u + 0x7fffu + ((v.u >> 16) & 1u)) >> 16;  // RNE
  return (u16)r;
}

// ---------------- Kernel 0: zero the column-sumsq accumulator ----------------
__global__ void k_zero(float* __restrict__ cn) {
  cn[blockIdx.x * 256 + threadIdx.x] = 0.f;
}

// ---------------- Kernel 1: row-l2norm of x -> bf16, one wave per row ----------------
__global__ void k_xnorm(const float* __restrict__ x, u16* __restrict__ xn) {
  int row = (blockIdx.x * blockDim.x + threadIdx.x) >> 6;
  int lane = threadIdx.x & 63;
  const float4* rp = (const float4*)(x + (size_t)row * K_DIM);
  float4 a = rp[lane];
  float4 b = rp[lane + 64];
  float s = a.x*a.x + a.y*a.y + a.z*a.z + a.w*a.w
          + b.x*b.x + b.y*b.y + b.z*b.z + b.w*b.w;
#pragma unroll
  for (int off = 32; off > 0; off >>= 1) s += __shfl_xor(s, off, 64);
  float r = rsqrtf(fmaxf(s, 1e-12f));
  ushort4 o0 = make_ushort4(f2bf(a.x*r), f2bf(a.y*r), f2bf(a.z*r), f2bf(a.w*r));
  ushort4 o1 = make_ushort4(f2bf(b.x*r), f2bf(b.y*r), f2bf(b.z*r), f2bf(b.w*r));
  ushort4* dst = (ushort4*)(xn + (size_t)row * K_DIM);
  dst[lane] = o0;
  dst[lane + 64] = o1;
}

// ---------------- Kernel 2: transpose + cast (UNNORMALIZED) + fused col-sumsq ----------------
__global__ void k_wtrans(const float* __restrict__ w, float* __restrict__ cn,
                         u16* __restrict__ wT) {
  __shared__ u16 tile[64][68];
  int c0 = blockIdx.x * 64;
  int r0 = blockIdx.y * 64;
  int tc = threadIdx.x & 63;
  int tw = threadIdx.x >> 6;  // 0..3
  float s = 0.f;
#pragma unroll
  for (int i = 0; i < 16; ++i) {
    int r = i * 4 + tw;
    float v = w[(size_t)(r0 + r) * N_DIM + c0 + tc];
    s = fmaf(v, v, s);
    tile[tc][r] = f2bf(v);
  }
  atomicAdd(&cn[c0 + tc], s);
  __syncthreads();
  int cc = threadIdx.x >> 4;        // 0..15
  int rr = (threadIdx.x & 15) * 4;  // 0..60
#pragma unroll
  for (int i = 0; i < 4; ++i) {
    int c = cc + i * 16;
    ushort4 v = *(const ushort4*)&tile[c][rr];
    *(ushort4*)(wT + (size_t)(c0 + c) * K_DIM + r0 + rr) = v;
  }
}

// ---------------- Kernel 3: PERSISTENT XCD-BANDED 128x128 GEMM, 2 blocks/CU (TLP) ----------------
// 512 blocks = 2/CU (64 KiB LDS, ~180 VGPR -> 8 waves/CU). XCD (b&7) owns bm
// band [xcd*8, xcd*8+8) -> A slice (1 MB) L2-resident. Worker blk = b>>3
// (0..63): bm = xcd*8 + (blk&7) FIXED, walks bn = (blk>>3) + 8*ti.
// One __syncthreads per kt; store bursts hidden by the sibling block (TLP).
__global__ __launch_bounds__(256, 2) void k_gemm(const u16* __restrict__ A,
                                                 const u16* __restrict__ Bt,
                                                 const float* __restrict__ cn,
                                                 float* __restrict__ C) {
  __shared__ u16 sm[2][16384];  // per buf: A [128][64] @0, B [128][64] @8192
  constexpr int BOFF = 8192;

  const int b = blockIdx.x;
  const int xcd = b & 7;
  const int blk = b >> 3;              // 0..63 worker within XCD
  const int bm = xcd * 8 + (blk & 7);  // FIXED per worker
  const int bn0 = blk >> 3;            // 0..7
  const int cnt = (bn0 < 2) ? 32 : 31; // bn = bn0 + 8*ti < 250

  const int tid = threadIdx.x;
  const int lane = tid & 63;
  const int w = tid >> 6;   // 0..3
  const int wr = w >> 1;    // 0..1 (64-row half)
  const int wc = w & 1;     // 0..1 (64-col half)
  const int la = lane & 15;
  const int lk = lane >> 4;
  const int rx = la & 7;
  const int s0 = ((0 + lk) ^ rx) * 8;  // swizzled elem-col, kk=0
  const int s1 = ((4 + lk) ^ rx) * 8;  // swizzled elem-col, kk=32

  // staging (rule #21: linear LDS dest + inverse-swizzled global src)
  const int srow = tid >> 3;                    // 0..31 (+ i*32)
  const int sgl = ((tid & 7) ^ (srow & 7)) * 8; // pre-swizzled global elem col
  const int ldst = srow * 64 + (tid & 7) * 8;   // linear LDS elem offset
  const int arow0 = (wr * 64 + la) * 64;        // + m*1024
  const int brow0 = (wc * 64 + la) * 64;        // + n*1024

  const u16* ag = A + (size_t)(bm * 128 + srow) * K_DIM + sgl;  // fixed all run
  int bn = bn0;
  const u16* bg = Bt + (size_t)(bn * 128 + srow) * K_DIM + sgl;
  constexpr size_t BSTEP = (size_t)8 * 128 * K_DIM;  // bn += 8

  f32x4 acc[4][4] = {};

#define GLL(p, eoff)                                                              \
  __builtin_amdgcn_global_load_lds(                                              \
      (const __attribute__((address_space(1))) void*)(p),                        \
      (__attribute__((address_space(3))) void*)&sm[0][(eoff)], 16, 0, 0)

  // prologue: stage (tile0, kt=0) into buf 0
#pragma unroll
  for (int i = 0; i < 4; ++i) GLL(ag + (size_t)i * 32 * K_DIM, i * 2048 + ldst);
#pragma unroll
  for (int i = 0; i < 4; ++i) GLL(bg + (size_t)i * 32 * K_DIM, BOFF + i * 2048 + ldst);
  __syncthreads();

  for (int ti = 0; ti < cnt; ++ti) {
    const bool last_tile = (ti + 1 == cnt);

    for (int kt = 0; kt < 8; ++kt) {
      const int cur = kt & 1;
      const int nxt = cur ^ 1;
      const bool pf = (kt < 7) || !last_tile;
      const u16* agk = (kt < 7) ? (ag + (kt + 1) * 64) : ag;           // next tile: same A panel
      const u16* bgk = (kt < 7) ? (bg + (kt + 1) * 64) : (bg + BSTEP); // next tile: bn+8

      // stage next K-step (issue early; drained by the kt-end __syncthreads)
      if (pf) {
        const int nb = nxt * 16384;
#pragma unroll
        for (int i = 0; i < 4; ++i) GLL(agk + (size_t)i * 32 * K_DIM, nb + i * 2048 + ldst);
#pragma unroll
        for (int i = 0; i < 4; ++i) GLL(bgk + (size_t)i * 32 * K_DIM, nb + BOFF + i * 2048 + ldst);
      }

      // read all fragments of the current buffer
      bf16x8 af[4][2], bf[4][2];
#pragma unroll
      for (int m = 0; m < 4; ++m) {
        af[m][0] = *(const bf16x8*)&sm[cur][arow0 + m * 1024 + s0];
        af[m][1] = *(const bf16x8*)&sm[cur][arow0 + m * 1024 + s1];
      }
#pragma unroll
      for (int n = 0; n < 4; ++n) {
        bf[n][0] = *(const bf16x8*)&sm[cur][BOFF + brow0 + n * 1024 + s0];
        bf[n][1] = *(const bf16x8*)&sm[cur][BOFF + brow0 + n * 1024 + s1];
      }

#pragma unroll
      for (int m = 0; m < 4; ++m)
#pragma unroll
        for (int n = 0; n < 4; ++n) {
          acc[m][n] = __builtin_amdgcn_mfma_f32_16x16x32_bf16(af[m][0], bf[n][0], acc[m][n], 0, 0, 0);
          acc[m][n] = __builtin_amdgcn_mfma_f32_16x16x32_bf16(af[m][1], bf[n][1], acc[m][n], 0, 0, 0);
        }

      __syncthreads();  // buf[nxt] staged + all reads of buf[cur] done
    }

    // ---- tile epilogue: scale by rsqrt(col sumsq), fire-and-forget NT stores ----
    {
      const size_t crow0 = (size_t)bm * 128 + wr * 64 + lk * 4;
      const int ccol0 = bn * 128 + wc * 64 + la;
      float rs[4];
#pragma unroll
      for (int n = 0; n < 4; ++n)
        rs[n] = rsqrtf(fmaxf(cn[ccol0 + n * 16], 1e-12f));
#pragma unroll
      for (int m = 0; m < 4; ++m)
#pragma unroll
        for (int j = 0; j < 4; ++j) {
          float* cp = C + (crow0 + m * 16 + j) * N_DIM + ccol0;
#pragma unroll
          for (int n = 0; n < 4; ++n)
            __builtin_nontemporal_store(acc[m][n][j] * rs[n], cp + n * 16);
        }
#pragma unroll
      for (int m = 0; m < 4; ++m)
#pragma unroll
        for (int n = 0; n < 4; ++n)
          acc[m][n] = (f32x4){0.f, 0.f, 0.f, 0.f};
    }

    bn += 8;
    bg += BSTEP;
  }
#undef GLL
}

// ---------------- launch ----------------
extern "C" void kernel_launch(void* const* d_in, const int* in_sizes, int n_in,
                              void* d_out, int out_size, void* d_ws, size_t ws_size,
                              hipStream_t stream) {
  const float* x = (const float*)d_in[0];   // [8192, 512]
  const float* w = (const float*)d_in[1];   // [512, 32000]
  float* out = (float*)d_out;               // [8192, 32000]

  char* ws = (char*)d_ws;
  float* cn = (float*)ws;                                    // 32000 f32 (sumsq)
  u16* xn = (u16*)(ws + 131072);                             // 8192*512 bf16
  u16* wT = (u16*)(ws + 131072 + (size_t)M_DIM * K_DIM * 2); // 32000*512 bf16

  k_zero<<<N_DIM / 256, 256, 0, stream>>>(cn);
  k_xnorm<<<M_DIM / 4, 256, 0, stream>>>(x, xn);
  k_wtrans<<<dim3(N_DIM / 64, K_DIM / 64), 256, 0, stream>>>(w, cn, wT);
  k_gemm<<<512, 256, 0, stream>>>(xn, wT, cn, out);
}